// Round 18
// baseline (557.399 us; speedup 1.0000x reference)
//
#include <hip/hip_runtime.h>

typedef __bf16 bf16;
typedef bf16 bf16x4 __attribute__((ext_vector_type(4)));
typedef bf16 bf16x8 __attribute__((ext_vector_type(8)));
typedef float f32x4 __attribute__((ext_vector_type(4)));

// ws layout (bf16 elements):
//   PK1 [4][4][4][64][8]  = 32768   (GEMM1 weights, fragment-packed)
//   PK2 [4][8][4][64][8]  = 65536   (W1)
//   PK3 [4][8][4][64][8]  = 65536   (W2)
//   QG  bf16[64][256]     = 16384   (gate table)
#define WS_PK1   0
#define WS_PK2   32768
#define WS_PK3   98304
#define WS_QG    163840

// ---------- prep: pack weights into per-(cg,kk,ai) contiguous 1KB fragments ----------
__global__ void prep_weights(const float* __restrict__ Wrel,
                             const float* __restrict__ Wnode,
                             const float* __restrict__ W1,
                             const float* __restrict__ W2,
                             bf16* __restrict__ ws) {
  int id = blockIdx.x * 256 + threadIdx.x;
  if (id < 32768) {                       // PK1: cg(4) kk(4) ai(4) l(64) j(8)
    int cg = id >> 13, rem = id & 8191;
    int kk = rem >> 11;
    int ai = (rem >> 9) & 3;
    int l  = (rem >> 3) & 63;
    int j  = rem & 7;
    int n  = (cg & 1) * 64 + ai * 16 + (l & 15);
    int k  = kk * 32 + (l >> 4) * 8 + j;
    const float* src = (cg >> 1) ? Wnode : Wrel;
    ws[WS_PK1 + id] = (bf16)src[k * 128 + n];
  } else if (id < 98304) {                // PK2: cg(4) kk(8) ai(4) l(64) j(8)
    int t = id - 32768;
    int cg = t >> 14, rem = t & 16383;
    int kk = rem >> 11;
    int ai = (rem >> 9) & 3;
    int l  = (rem >> 3) & 63;
    int j  = rem & 7;
    int n  = cg * 64 + ai * 16 + (l & 15);
    int k  = kk * 32 + (l >> 4) * 8 + j;
    ws[WS_PK2 + t] = (bf16)W1[k * 256 + n];
  } else if (id < 163840) {               // PK3
    int t = id - 98304;
    int cg = t >> 14, rem = t & 16383;
    int kk = rem >> 11;
    int ai = (rem >> 9) & 3;
    int l  = (rem >> 3) & 63;
    int j  = rem & 7;
    int n  = cg * 64 + ai * 16 + (l & 15);
    int k  = kk * 32 + (l >> 4) * 8 + j;
    ws[WS_PK3 + t] = (bf16)W2[k * 256 + n];
  }
}

// ---------- prep: qg[64][256] = sigmoid(question @ W_qgate), bf16 ----------
__global__ void prep_qg(const float* __restrict__ question,
                        const float* __restrict__ Wq,
                        bf16* __restrict__ qg) {
  int b = blockIdx.x, c = threadIdx.x;
  float s = 0.f;
#pragma unroll 8
  for (int k = 0; k < 128; ++k) s += question[b * 128 + k] * Wq[k * 256 + c];
  qg[b * 256 + c] = (bf16)(1.f / (1.f + expf(-s)));
}

// tanh-form GELU: max |diff vs erf-GELU| ~5e-4, far under 1.23e-2 budget
__device__ __forceinline__ float gelu_fast(float x) {
  float x2 = x * x;
  float p = fmaf(0.0356774081f, x2, 0.7978845608f);
  float y = p * x;
  float e = __expf(2.f * y);
  float r = __builtin_amdgcn_rcpf(e + 1.f);
  float th = 1.f - 2.f * r;
  return 0.5f * x * (1.f + th);
}

typedef __attribute__((address_space(1))) const void gq_t;
typedef __attribute__((address_space(3))) void lq_t;
#define GLD16(g, s) __builtin_amdgcn_global_load_lds((gq_t*)(g), (lq_t*)(s), 16, 0, 0)
#define SBF() __builtin_amdgcn_sched_barrier(0xF)
#define WAIT_VM(n)   { asm volatile("s_waitcnt vmcnt(" #n ")" ::: "memory"); SBF(); }
#define WAIT_LGKM0() { asm volatile("s_waitcnt lgkmcnt(0)" ::: "memory"); SBF(); }
#define BAR() __builtin_amdgcn_s_barrier()

// ---------- main: 64 edges/tile, 4 waves (1 cg each), grid-stride, 2 blocks/CU ----------
// R12 body (2-slot gld_lds weight FIFO, counted vmcnt) + CROSS-TILE PREFETCH:
// next tile's tail/ebatch injected into G1-kk0 (ledger-adjusted waits), next
// tile's rel/node/gate loads issued at G3's vmcnt(0) point, token LDS-write in
// the store epilogue (post-BAR: union lifecycle preserved).
__global__ __launch_bounds__(256, 2) void fused_main(
    const float* __restrict__ rel_tok,   // [E,128]
    const float* __restrict__ node_tok,  // [N,128]
    const int*   __restrict__ tail_idx,  // edge_index + E
    const int*   __restrict__ ebatch,    // [E]
    const bf16*  __restrict__ pk1,
    const bf16*  __restrict__ pk2,
    const bf16*  __restrict__ pk3,
    const bf16*  __restrict__ qg,        // [64][256] bf16
    const float* __restrict__ b1,
    const float* __restrict__ b2,
    float* __restrict__ out,             // [E,256]
    int ntiles, int G)
{
  __shared__ char  s_buf[32768];   // tokens [2][64][128] / AK,H [64][256] union
  __shared__ char  s_w[32768];     // [slot 2][cg 4][4KB]
  __shared__ float s_bias[512];    // b1 | b2

  const int tid = threadIdx.x;
  const int cg  = tid >> 6;
  const int l   = tid & 63;
  const int lo  = l & 15;
  const int hi  = l >> 4;
  const int h1  = cg >> 1;
  const int c4s = tid & 31;        // c4 for staging (tid+i*256 ≡ tid mod 32)

  auto issue_step = [&](int s) {   // s literal after unroll
    const bf16* g;
    if (s < 4)       g = pk1 + cg * 8192  + s * 2048;
    else if (s < 12) g = pk2 + cg * 16384 + (s - 4) * 2048;
    else             g = pk3 + cg * 16384 + (s - 12) * 2048;
    g += l * 8;
    char* d = s_w + (s & 1) * 16384 + cg * 4096;
#pragma unroll
    for (int ai = 0; ai < 4; ++ai) GLD16(g + ai * 512, d + ai * 1024);
  };

  s_bias[tid]       = b1[tid];
  s_bias[256 + tid] = b2[tid];

  // ---------- first tile: serial staging ----------
  const int t0 = blockIdx.x;
  bf16x4 gv[4][4];
  {
    int ebv[4];
#pragma unroll
    for (int bj = 0; bj < 4; ++bj) ebv[bj] = ebatch[t0 * 64 + bj * 16 + lo];
#pragma unroll
    for (int bj = 0; bj < 4; ++bj)
#pragma unroll
      for (int ai = 0; ai < 4; ++ai)
        gv[bj][ai] = *(const bf16x4*)(qg + ebv[bj] * 256 + cg * 64 + ai * 16 + hi * 4);
    const float4* g = (const float4*)rel_tok + (size_t)t0 * 2048;
#pragma unroll
    for (int i = 0; i < 8; ++i) {
      int row = (tid >> 5) + 8 * i;
      float4 v = g[tid + i * 256];
      bf16x4 b; b[0] = (bf16)v.x; b[1] = (bf16)v.y; b[2] = (bf16)v.z; b[3] = (bf16)v.w;
      int off = row * 256 + ((c4s * 8) ^ ((row & 15) << 4));
      *(bf16x4*)(s_buf + off) = b;
    }
#pragma unroll
    for (int i = 0; i < 8; ++i) {
      int row = (tid >> 5) + 8 * i;
      int tail = tail_idx[t0 * 64 + row];
      float4 v = ((const float4*)node_tok)[(size_t)tail * 32 + c4s];
      bf16x4 b; b[0] = (bf16)v.x; b[1] = (bf16)v.y; b[2] = (bf16)v.z; b[3] = (bf16)v.w;
      int off = 16384 + row * 256 + ((c4s * 8) ^ ((row & 15) << 4));
      *(bf16x4*)(s_buf + off) = b;
    }
  }

  const f32x4 zero4 = {0.f, 0.f, 0.f, 0.f};
  const int wrd = cg * 4096 + l * 16;

  for (int t = t0; t < ntiles; t += G) {
    const int base = t * 64;
    int tn = t + G; if (tn >= ntiles) tn = t;   // clamp: harmless dummy prefetch

    WAIT_VM(0);                        // drain prev stores/staging
    issue_step(0);
    issue_step(1);
    WAIT_LGKM0();                      // token/bias ds_writes done
    BAR();                             // B_a

    int t2l[8], eb2v[4];
    bf16x4 gv2[4][4];

    // ================= GEMM1: steps 0..3 =================
    f32x4 acc1[4][4];
#pragma unroll
    for (int ai = 0; ai < 4; ++ai)
#pragma unroll
      for (int bj = 0; bj < 4; ++bj) acc1[ai][bj] = zero4;

#pragma unroll
    for (int kk = 0; kk < 4; ++kk) {
      if (kk == 0)      { WAIT_VM(4); }
      else if (kk < 3)  { WAIT_VM(16); }   // step(kk-? ) done; 12 injected + next step left
      else              { WAIT_VM(4); }    // forces injected loads retired
      bf16x8 a[4];
#pragma unroll
      for (int ai = 0; ai < 4; ++ai)
        a[ai] = *(const bf16x8*)(s_w + (kk & 1) * 16384 + wrd + ai * 1024);
      WAIT_LGKM0();
      issue_step(kk + 2);
      if (kk == 0) {                   // inject next-tile tail/ebatch (12 loads)
        SBF();
#pragma unroll
        for (int i = 0; i < 8; ++i) t2l[i] = tail_idx[tn * 64 + (tid >> 5) + 8 * i];
#pragma unroll
        for (int bj = 0; bj < 4; ++bj) eb2v[bj] = ebatch[tn * 64 + bj * 16 + lo];
        SBF();
      }
      __builtin_amdgcn_s_setprio(1);
#pragma unroll
      for (int bj = 0; bj < 4; ++bj) {
        int e = bj * 16 + lo;
        bf16x8 b = *(const bf16x8*)(s_buf + h1 * 16384 + e * 256 +
                                    ((kk * 64 + hi * 16) ^ ((e & 15) << 4)));
#pragma unroll
        for (int ai = 0; ai < 4; ++ai)
          acc1[ai][bj] = __builtin_amdgcn_mfma_f32_16x16x32_bf16(a[ai], b, acc1[ai][bj], 0, 0, 0);
      }
      __builtin_amdgcn_s_setprio(0);
    }
    BAR();                             // B_b: token reads done

    // gate + pack -> AK
#pragma unroll
    for (int bj = 0; bj < 4; ++bj) {
      int e = bj * 16 + lo;
#pragma unroll
      for (int ai = 0; ai < 4; ++ai) {
        int col0 = cg * 64 + ai * 16 + hi * 4;
        bf16x4 pk;
        pk[0] = (bf16)(acc1[ai][bj][0] * (float)gv[bj][ai][0]);
        pk[1] = (bf16)(acc1[ai][bj][1] * (float)gv[bj][ai][1]);
        pk[2] = (bf16)(acc1[ai][bj][2] * (float)gv[bj][ai][2]);
        pk[3] = (bf16)(acc1[ai][bj][3] * (float)gv[bj][ai][3]);
        int off = e * 512 + ((2 * col0) ^ ((e & 15) << 4));
        *(bf16x4*)(s_buf + off) = pk;
      }
    }
    WAIT_LGKM0();
    BAR();                             // B_c: AK visible

    // ================= GEMM2: steps 4..11 =================
    f32x4 acc2[4][4];
#pragma unroll
    for (int ai = 0; ai < 4; ++ai)
#pragma unroll
      for (int bj = 0; bj < 4; ++bj) acc2[ai][bj] = zero4;

#pragma unroll
    for (int kk = 0; kk < 8; ++kk) {
      const int s = 4 + kk;
      WAIT_VM(4);
      bf16x8 a[4];
#pragma unroll
      for (int ai = 0; ai < 4; ++ai)
        a[ai] = *(const bf16x8*)(s_w + (s & 1) * 16384 + wrd + ai * 1024);
      WAIT_LGKM0();
      issue_step(s + 2);
      __builtin_amdgcn_s_setprio(1);
#pragma unroll
      for (int bj = 0; bj < 4; ++bj) {
        int e = bj * 16 + lo;
        bf16x8 b = *(const bf16x8*)(s_buf + e * 512 +
                                    ((kk * 64 + hi * 16) ^ ((e & 15) << 4)));
#pragma unroll
        for (int ai = 0; ai < 4; ++ai)
          acc2[ai][bj] = __builtin_amdgcn_mfma_f32_16x16x32_bf16(a[ai], b, acc2[ai][bj], 0, 0, 0);
      }
      __builtin_amdgcn_s_setprio(0);
    }
    BAR();                             // B_d: AK reads done

    // gelu + bias -> H
#pragma unroll
    for (int bj = 0; bj < 4; ++bj) {
      int e = bj * 16 + lo;
#pragma unroll
      for (int ai = 0; ai < 4; ++ai) {
        int col0 = cg * 64 + ai * 16 + hi * 4;
        float4 bv = *(const float4*)(s_bias + col0);
        bf16x4 pk;
        pk[0] = (bf16)gelu_fast(acc2[ai][bj][0] + bv.x);
        pk[1] = (bf16)gelu_fast(acc2[ai][bj][1] + bv.y);
        pk[2] = (bf16)gelu_fast(acc2[ai][bj][2] + bv.z);
        pk[3] = (bf16)gelu_fast(acc2[ai][bj][3] + bv.w);
        int off = e * 512 + ((2 * col0) ^ ((e & 15) << 4));
        *(bf16x4*)(s_buf + off) = pk;
      }
    }
    WAIT_LGKM0();
    BAR();                             // B_e: H visible

    // ================= GEMM3: steps 12..19 + prefetch cluster =================
    f32x4 acc3[4][4];
#pragma unroll
    for (int ai = 0; ai < 4; ++ai)
#pragma unroll
      for (int bj = 0; bj < 4; ++bj) acc3[ai][bj] = zero4;

    float4 rv[8], nv[8];

#pragma unroll
    for (int kk = 0; kk < 8; ++kk) {
      const int s = 12 + kk;
      if (s < 19) { WAIT_VM(4); } else { WAIT_VM(0); }
      bf16x8 a[4];
#pragma unroll
      for (int ai = 0; ai < 4; ++ai)
        a[ai] = *(const bf16x8*)(s_w + (s & 1) * 16384 + wrd + ai * 1024);
      WAIT_LGKM0();
      if (s + 2 <= 19) issue_step(s + 2);
      if (s == 19) {
        // queue is clean: issue next-tile rel(8) + node(8) + gate(16) loads
        SBF();
        const float4* gr = (const float4*)rel_tok + (size_t)tn * 2048;
#pragma unroll
        for (int i = 0; i < 8; ++i) rv[i] = gr[tid + i * 256];
#pragma unroll
        for (int i = 0; i < 8; ++i)
          nv[i] = ((const float4*)node_tok)[(size_t)t2l[i] * 32 + c4s];
#pragma unroll
        for (int bj = 0; bj < 4; ++bj)
#pragma unroll
          for (int ai = 0; ai < 4; ++ai)
            gv2[bj][ai] = *(const bf16x4*)(qg + eb2v[bj] * 256 + cg * 64 + ai * 16 + hi * 4);
        SBF();
      }
      __builtin_amdgcn_s_setprio(1);
#pragma unroll
      for (int bj = 0; bj < 4; ++bj) {
        int e = bj * 16 + lo;
        bf16x8 b = *(const bf16x8*)(s_buf + e * 512 +
                                    ((kk * 64 + hi * 16) ^ ((e & 15) << 4)));
#pragma unroll
        for (int ai = 0; ai < 4; ++ai)
          acc3[ai][bj] = __builtin_amdgcn_mfma_f32_16x16x32_bf16(a[ai], b, acc3[ai][bj], 0, 0, 0);
      }
      __builtin_amdgcn_s_setprio(0);
    }
    BAR();                             // all H reads done -> s_buf free

    // stores (16), then wait loads (leave stores), then write next tokens
#pragma unroll
    for (int bj = 0; bj < 4; ++bj) {
      int e = bj * 16 + lo;
#pragma unroll
      for (int ai = 0; ai < 4; ++ai) {
        int col0 = cg * 64 + ai * 16 + hi * 4;
        float4 bv = *(const float4*)(s_bias + 256 + col0);
        float4 o;
        o.x = acc3[ai][bj][0] + bv.x;
        o.y = acc3[ai][bj][1] + bv.y;
        o.z = acc3[ai][bj][2] + bv.z;
        o.w = acc3[ai][bj][3] + bv.w;
        *(float4*)(out + (size_t)(base + e) * 256 + col0) = o;
      }
    }
    SBF();
    WAIT_VM(16);                       // 32 loads retired; 16 stores in flight
#pragma unroll
    for (int i = 0; i < 8; ++i) {
      int row = (tid >> 5) + 8 * i;
      float4 v = rv[i];
      bf16x4 b; b[0] = (bf16)v.x; b[1] = (bf16)v.y; b[2] = (bf16)v.z; b[3] = (bf16)v.w;
      int off = row * 256 + ((c4s * 8) ^ ((row & 15) << 4));
      *(bf16x4*)(s_buf + off) = b;
      float4 u = nv[i];
      bf16x4 c; c[0] = (bf16)u.x; c[1] = (bf16)u.y; c[2] = (bf16)u.z; c[3] = (bf16)u.w;
      *(bf16x4*)(s_buf + 16384 + off) = c;
    }
#pragma unroll
    for (int bj = 0; bj < 4; ++bj)
#pragma unroll
      for (int ai = 0; ai < 4; ++ai) gv[bj][ai] = gv2[bj][ai];
  }
}

extern "C" void kernel_launch(void* const* d_in, const int* in_sizes, int n_in,
                              void* d_out, int out_size, void* d_ws, size_t ws_size,
                              hipStream_t stream) {
  const float* rel    = (const float*)d_in[0];
  const float* node   = (const float*)d_in[1];
  const int*   eidx   = (const int*)d_in[2];
  const float* quest  = (const float*)d_in[3];
  const int*   ebat   = (const int*)d_in[4];
  const float* Wrel   = (const float*)d_in[5];
  const float* Wnode  = (const float*)d_in[6];
  const float* Wq     = (const float*)d_in[7];
  const float* W1     = (const float*)d_in[8];
  const float* bias1  = (const float*)d_in[9];
  const float* W2     = (const float*)d_in[10];
  const float* bias2  = (const float*)d_in[11];
  float* outp = (float*)d_out;
  bf16* ws = (bf16*)d_ws;

  const int E = in_sizes[4];  // 400000
  const int ntiles = E / 64;  // 6250
  const int G = 512;          // 2 blocks/CU, ~12 tiles each

  prep_weights<<<640, 256, 0, stream>>>(Wrel, Wnode, W1, W2, ws);
  prep_qg<<<64, 256, 0, stream>>>(quest, Wq, ws + WS_QG);
  fused_main<<<G, 256, 0, stream>>>(
      rel, node, eidx + E, ebat,
      ws + WS_PK1, ws + WS_PK2, ws + WS_PK3, ws + WS_QG,
      bias1, bias2, outp, ntiles, G);
}

// Round 19
// 278.854 us; speedup vs baseline: 1.9989x; 1.9989x over previous
//
#include <hip/hip_runtime.h>

typedef __bf16 bf16;
typedef bf16 bf16x4 __attribute__((ext_vector_type(4)));
typedef bf16 bf16x8 __attribute__((ext_vector_type(8)));
typedef float f32x4 __attribute__((ext_vector_type(4)));

// ws layout (bf16 elements):
//   PK1 [4][4][4][64][8]  = 32768   (GEMM1 weights, fragment-packed)
//   PK2 [4][8][4][64][8]  = 65536   (W1)
//   PK3 [4][8][4][64][8]  = 65536   (W2)
//   QG  float[64][256] at bf16-offset 163840 (64KB)
#define WS_PK1   0
#define WS_PK2   32768
#define WS_PK3   98304
#define WS_QG_F  163840

// ---------- prep: pack weights into per-(cg,kk,ai) contiguous 1KB fragments ----------
__global__ void prep_weights(const float* __restrict__ Wrel,
                             const float* __restrict__ Wnode,
                             const float* __restrict__ W1,
                             const float* __restrict__ W2,
                             bf16* __restrict__ ws) {
  int id = blockIdx.x * 256 + threadIdx.x;
  if (id < 32768) {                       // PK1: cg(4) kk(4) ai(4) l(64) j(8)
    int cg = id >> 13, rem = id & 8191;
    int kk = rem >> 11;
    int ai = (rem >> 9) & 3;
    int l  = (rem >> 3) & 63;
    int j  = rem & 7;
    int n  = (cg & 1) * 64 + ai * 16 + (l & 15);
    int k  = kk * 32 + (l >> 4) * 8 + j;
    const float* src = (cg >> 1) ? Wnode : Wrel;
    ws[WS_PK1 + id] = (bf16)src[k * 128 + n];
  } else if (id < 98304) {                // PK2: cg(4) kk(8) ai(4) l(64) j(8)
    int t = id - 32768;
    int cg = t >> 14, rem = t & 16383;
    int kk = rem >> 11;
    int ai = (rem >> 9) & 3;
    int l  = (rem >> 3) & 63;
    int j  = rem & 7;
    int n  = cg * 64 + ai * 16 + (l & 15);
    int k  = kk * 32 + (l >> 4) * 8 + j;
    ws[WS_PK2 + t] = (bf16)W1[k * 256 + n];
  } else if (id < 163840) {               // PK3
    int t = id - 98304;
    int cg = t >> 14, rem = t & 16383;
    int kk = rem >> 11;
    int ai = (rem >> 9) & 3;
    int l  = (rem >> 3) & 63;
    int j  = rem & 7;
    int n  = cg * 64 + ai * 16 + (l & 15);
    int k  = kk * 32 + (l >> 4) * 8 + j;
    ws[WS_PK3 + t] = (bf16)W2[k * 256 + n];
  }
}

// ---------- prep: qg[64][256] = sigmoid(question @ W_qgate), fp32 ----------
__global__ void prep_qg(const float* __restrict__ question,
                        const float* __restrict__ Wq,
                        float* __restrict__ qgf) {
  int b = blockIdx.x, c = threadIdx.x;
  float s = 0.f;
#pragma unroll 8
  for (int k = 0; k < 128; ++k) s += question[b * 128 + k] * Wq[k * 256 + c];
  qgf[b * 256 + c] = 1.f / (1.f + expf(-s));
}

// tanh-form GELU, exp2-direct: gelu(x) = x - x/(1 + 2^(x*(c1*x^2+c2)))
// where c1 = 2.88539*0.0356774, c2 = 2.88539*0.7978846 (2/ln2 folding).
// max |diff vs erf-GELU| ~5e-4, far under 1.23e-2 budget.
__device__ __forceinline__ float gelu_fast(float x) {
  float m = x * x;
  float t = fmaf(0.10294537f, m, 2.30220790f);
  float e = __builtin_amdgcn_exp2f(t * x);
  float r = __builtin_amdgcn_rcpf(e + 1.f);
  return x - x * r;
}

typedef __attribute__((address_space(1))) const void gq_t;
typedef __attribute__((address_space(3))) void lq_t;
#define GLD16(g, s) __builtin_amdgcn_global_load_lds((gq_t*)(g), (lq_t*)(s), 16, 0, 0)
// sched_barrier mask 0xF = ALU|VALU|SALU|MFMA may cross; DS/VMEM pinned.
#define SB() __builtin_amdgcn_sched_barrier(0xF)
#define WAIT_VM4()   { asm volatile("s_waitcnt vmcnt(4)" ::: "memory"); SB(); }
#define WAIT_VM0()   { asm volatile("s_waitcnt vmcnt(0)" ::: "memory"); SB(); }
#define WAIT_LGKM0() { asm volatile("s_waitcnt lgkmcnt(0)" ::: "memory"); SB(); }
#define BAR() __builtin_amdgcn_s_barrier()

// ---------- main: 64 edges/block, 4 waves (1 cg each), 2 blocks/CU ----------
// R12 champion structure: wave-private 2-slot weight FIFO in LDS fed by
// global_load_lds, depth-2 counted vmcnt (never drained mid-loop).
// 67.5KB LDS -> 2 blocks/CU so barrier/staging stalls cross-hide.
// R19: exp2-direct GELU + fp32 gate table (no cvt in gate phase).
__global__ __launch_bounds__(256, 2) void fused_main(
    const float* __restrict__ rel_tok,   // [E,128]
    const float* __restrict__ node_tok,  // [N,128]
    const int*   __restrict__ tail_idx,  // edge_index + E
    const int*   __restrict__ ebatch,    // [E]
    const bf16*  __restrict__ pk1,
    const bf16*  __restrict__ pk2,
    const bf16*  __restrict__ pk3,
    const float* __restrict__ qgf,       // [64][256] fp32
    const float* __restrict__ b1,
    const float* __restrict__ b2,
    float* __restrict__ out)             // [E,256]
{
  // s_buf 32KB union: tokens [2][64][128] bf16 (h*16384 + e*256 + swz)
  //                   AK/H   [64][256]    bf16 (e*512 + swz)
  // s_w   32KB: [slot 2][cg 4][4KB]
  __shared__ char  s_buf[32768];
  __shared__ char  s_w[32768];
  __shared__ float s_bias[512];          // b1 | b2

  const int tid = threadIdx.x;
  const int cg  = tid >> 6;       // wave = col group, cols [cg*64, cg*64+64)
  const int l   = tid & 63;
  const int lo  = l & 15;
  const int hi  = l >> 4;
  const int base = blockIdx.x * 64;
  const int h1  = cg >> 1;        // GEMM1 half (0=rel, 1=node)

  auto issue_step = [&](int s) {   // s compile-time after unroll
    const bf16* g;
    if (s < 4)       g = pk1 + cg * 8192  + s * 2048;
    else if (s < 12) g = pk2 + cg * 16384 + (s - 4) * 2048;
    else             g = pk3 + cg * 16384 + (s - 12) * 2048;
    g += l * 8;
    char* d = s_w + (s & 1) * 16384 + cg * 4096;
#pragma unroll
    for (int ai = 0; ai < 4; ++ai) GLD16(g + ai * 512, d + ai * 1024);
  };

  // ---- pre-FIFO VMEM: fp32 gate fragments (64 VGPR, dead by B_c), biases -> LDS ----
  int ebv[4];
#pragma unroll
  for (int bj = 0; bj < 4; ++bj) ebv[bj] = ebatch[base + bj * 16 + lo];
  float4 gv[4][4];
#pragma unroll
  for (int bj = 0; bj < 4; ++bj)
#pragma unroll
    for (int ai = 0; ai < 4; ++ai)
      gv[bj][ai] = *(const float4*)(qgf + ebv[bj] * 256 + cg * 64 + ai * 16 + hi * 4);
  s_bias[tid]       = b1[tid];
  s_bias[256 + tid] = b2[tid];

  // ---- stage tokens -> LDS bf16 ((row&15) XOR swizzle) ----
  {
    const float4* g = (const float4*)rel_tok + (size_t)base * 32;
#pragma unroll
    for (int i = 0; i < 8; ++i) {
      int idx = tid + i * 256;          // over [64][32] float4
      int row = idx >> 5, c4 = idx & 31;
      float4 v = g[idx];
      bf16x4 b; b[0] = (bf16)v.x; b[1] = (bf16)v.y; b[2] = (bf16)v.z; b[3] = (bf16)v.w;
      int off = row * 256 + ((c4 * 8) ^ ((row & 15) << 4));
      *(bf16x4*)(s_buf + off) = b;
    }
#pragma unroll
    for (int i = 0; i < 8; ++i) {
      int idx = tid + i * 256;
      int row = idx >> 5, c4 = idx & 31;
      int tail = tail_idx[base + row];  // 32 lanes same addr
      float4 v = ((const float4*)node_tok)[(size_t)tail * 32 + c4];
      bf16x4 b; b[0] = (bf16)v.x; b[1] = (bf16)v.y; b[2] = (bf16)v.z; b[3] = (bf16)v.w;
      int off = 16384 + row * 256 + ((c4 * 8) ^ ((row & 15) << 4));
      *(bf16x4*)(s_buf + off) = b;
    }
  }

  WAIT_VM0();                           // clean vmcnt slate before FIFO starts
  issue_step(0);
  issue_step(1);
  WAIT_LGKM0();                         // token/bias LDS writes done
  BAR();                                // B_a: tokens + biases visible

  const f32x4 zero4 = {0.f, 0.f, 0.f, 0.f};
  const int wb = cg * 4096 + l * 16;    // lane's read offset within a slot half

  // ================= GEMM1: steps 0..3, b from token region =================
  f32x4 acc1[4][4];
#pragma unroll
  for (int ai = 0; ai < 4; ++ai)
#pragma unroll
    for (int bj = 0; bj < 4; ++bj) acc1[ai][bj] = zero4;

#pragma unroll
  for (int kk = 0; kk < 4; ++kk) {
    const int s = kk;
    WAIT_VM4();                         // step s resident (s+1 in flight)
    bf16x8 a[4];
#pragma unroll
    for (int ai = 0; ai < 4; ++ai)
      a[ai] = *(const bf16x8*)(s_w + (s & 1) * 16384 + wb + ai * 1024);
    WAIT_LGKM0();                       // a[] in regs before slot reuse
    issue_step(s + 2);
    __builtin_amdgcn_s_setprio(1);
#pragma unroll
    for (int bj = 0; bj < 4; ++bj) {
      int e = bj * 16 + lo;
      bf16x8 b = *(const bf16x8*)(s_buf + h1 * 16384 + e * 256 +
                                  ((kk * 64 + hi * 16) ^ ((e & 15) << 4)));
#pragma unroll
      for (int ai = 0; ai < 4; ++ai)
        acc1[ai][bj] = __builtin_amdgcn_mfma_f32_16x16x32_bf16(a[ai], b, acc1[ai][bj], 0, 0, 0);
    }
    __builtin_amdgcn_s_setprio(0);
  }
  BAR();                                // B_b: all token reads done

  // gate + pack -> AK over token buffer (fp32 gate: no cvt)
#pragma unroll
  for (int bj = 0; bj < 4; ++bj) {
    int e = bj * 16 + lo;
#pragma unroll
    for (int ai = 0; ai < 4; ++ai) {
      int col0 = cg * 64 + ai * 16 + hi * 4;
      bf16x4 pk;
      pk[0] = (bf16)(acc1[ai][bj][0] * gv[bj][ai].x);
      pk[1] = (bf16)(acc1[ai][bj][1] * gv[bj][ai].y);
      pk[2] = (bf16)(acc1[ai][bj][2] * gv[bj][ai].z);
      pk[3] = (bf16)(acc1[ai][bj][3] * gv[bj][ai].w);
      int off = e * 512 + ((2 * col0) ^ ((e & 15) << 4));
      *(bf16x4*)(s_buf + off) = pk;
    }
  }
  WAIT_LGKM0();
  BAR();                                // B_c: AK visible

  // ================= GEMM2: steps 4..11, b from AK =================
  f32x4 acc2[4][4];
#pragma unroll
  for (int ai = 0; ai < 4; ++ai)
#pragma unroll
    for (int bj = 0; bj < 4; ++bj) acc2[ai][bj] = zero4;

#pragma unroll
  for (int kk = 0; kk < 8; ++kk) {
    const int s = 4 + kk;
    WAIT_VM4();
    bf16x8 a[4];
#pragma unroll
    for (int ai = 0; ai < 4; ++ai)
      a[ai] = *(const bf16x8*)(s_w + (s & 1) * 16384 + wb + ai * 1024);
    WAIT_LGKM0();
    issue_step(s + 2);
    __builtin_amdgcn_s_setprio(1);
#pragma unroll
    for (int bj = 0; bj < 4; ++bj) {
      int e = bj * 16 + lo;
      bf16x8 b = *(const bf16x8*)(s_buf + e * 512 +
                                  ((kk * 64 + hi * 16) ^ ((e & 15) << 4)));
#pragma unroll
      for (int ai = 0; ai < 4; ++ai)
        acc2[ai][bj] = __builtin_amdgcn_mfma_f32_16x16x32_bf16(a[ai], b, acc2[ai][bj], 0, 0, 0);
    }
    __builtin_amdgcn_s_setprio(0);
  }
  BAR();                                // B_d: all AK reads done

  // gelu + bias -> H (bias from LDS: no VMEM in FIFO window)
#pragma unroll
  for (int bj = 0; bj < 4; ++bj) {
    int e = bj * 16 + lo;
#pragma unroll
    for (int ai = 0; ai < 4; ++ai) {
      int col0 = cg * 64 + ai * 16 + hi * 4;
      float4 bv = *(const float4*)(s_bias + col0);
      bf16x4 pk;
      pk[0] = (bf16)gelu_fast(acc2[ai][bj][0] + bv.x);
      pk[1] = (bf16)gelu_fast(acc2[ai][bj][1] + bv.y);
      pk[2] = (bf16)gelu_fast(acc2[ai][bj][2] + bv.z);
      pk[3] = (bf16)gelu_fast(acc2[ai][bj][3] + bv.w);
      int off = e * 512 + ((2 * col0) ^ ((e & 15) << 4));
      *(bf16x4*)(s_buf + off) = pk;
    }
  }
  WAIT_LGKM0();
  BAR();                                // B_e: H visible

  // ================= GEMM3: steps 12..19, b from H =================
  f32x4 acc3[4][4];
#pragma unroll
  for (int ai = 0; ai < 4; ++ai)
#pragma unroll
    for (int bj = 0; bj < 4; ++bj) acc3[ai][bj] = zero4;

#pragma unroll
  for (int kk = 0; kk < 8; ++kk) {
    const int s = 12 + kk;
    if (s < 19) { WAIT_VM4(); } else { WAIT_VM0(); }
    bf16x8 a[4];
#pragma unroll
    for (int ai = 0; ai < 4; ++ai)
      a[ai] = *(const bf16x8*)(s_w + (s & 1) * 16384 + wb + ai * 1024);
    WAIT_LGKM0();
    if (s + 2 <= 19) issue_step(s + 2);
    __builtin_amdgcn_s_setprio(1);
#pragma unroll
    for (int bj = 0; bj < 4; ++bj) {
      int e = bj * 16 + lo;
      bf16x8 b = *(const bf16x8*)(s_buf + e * 512 +
                                  ((kk * 64 + hi * 16) ^ ((e & 15) << 4)));
#pragma unroll
      for (int ai = 0; ai < 4; ++ai)
        acc3[ai][bj] = __builtin_amdgcn_mfma_f32_16x16x32_bf16(a[ai], b, acc3[ai][bj], 0, 0, 0);
    }
    __builtin_amdgcn_s_setprio(0);
  }

  // bias + store (float4, lanes hi=0..3 form 64B runs)
#pragma unroll
  for (int bj = 0; bj < 4; ++bj) {
    int e = bj * 16 + lo;
#pragma unroll
    for (int ai = 0; ai < 4; ++ai) {
      int col0 = cg * 64 + ai * 16 + hi * 4;
      float4 bv = *(const float4*)(s_bias + 256 + col0);
      float4 o;
      o.x = acc3[ai][bj][0] + bv.x;
      o.y = acc3[ai][bj][1] + bv.y;
      o.z = acc3[ai][bj][2] + bv.z;
      o.w = acc3[ai][bj][3] + bv.w;
      *(float4*)(out + (size_t)(base + e) * 256 + col0) = o;
    }
  }
}

extern "C" void kernel_launch(void* const* d_in, const int* in_sizes, int n_in,
                              void* d_out, int out_size, void* d_ws, size_t ws_size,
                              hipStream_t stream) {
  const float* rel    = (const float*)d_in[0];
  const float* node   = (const float*)d_in[1];
  const int*   eidx   = (const int*)d_in[2];
  const float* quest  = (const float*)d_in[3];
  const int*   ebat   = (const int*)d_in[4];
  const float* Wrel   = (const float*)d_in[5];
  const float* Wnode  = (const float*)d_in[6];
  const float* Wq     = (const float*)d_in[7];
  const float* W1     = (const float*)d_in[8];
  const float* bias1  = (const float*)d_in[9];
  const float* W2     = (const float*)d_in[10];
  const float* bias2  = (const float*)d_in[11];
  float* outp = (float*)d_out;
  bf16* ws = (bf16*)d_ws;
  float* qgf = (float*)(ws + WS_QG_F);

  const int E = in_sizes[4];  // 400000

  prep_weights<<<640, 256, 0, stream>>>(Wrel, Wnode, W1, W2, ws);
  prep_qg<<<64, 256, 0, stream>>>(quest, Wq, qgf);
  fused_main<<<E / 64, 256, 0, stream>>>(
      rel, node, eidx + E, ebat,
      ws + WS_PK1, ws + WS_PK2, ws + WS_PK3, qgf,
      bias1, bias2, outp);
}